// Round 1
// baseline (120.322 us; speedup 1.0000x reference)
//
#include <hip/hip_runtime.h>
#include <hip/hip_bf16.h>

#define B_ 8
#define C_ 96
#define H_ 64
#define W_ 96
#define DD 21            // displacements per axis
#define LDC 104          // padded channel stride (ushorts) in LDS / 16B-aligned
#define D2T_H 104        // 64 + 2*20
#define D2T_W 160        // 96 + 2*20 + 24 extra zero cols for n-tile overreach
#define LDST 100         // Dst row stride in floats (16B aligned, conflict-light)

typedef __attribute__((ext_vector_type(8))) short sh8;
typedef __attribute__((ext_vector_type(4))) float fx4;

__device__ __attribute__((aligned(16))) unsigned short g_d1T[B_*H_*W_*C_];
__device__ __attribute__((aligned(16))) unsigned short g_d2T[B_*D2T_H*D2T_W*C_];

__global__ __launch_bounds__(256) void zfill_d2T() {
  const int n = B_*D2T_H*D2T_W*C_/8;      // uint4 count
  uint4* p = (uint4*)g_d2T;
  uint4 z; z.x = z.y = z.z = z.w = 0u;
  for (int i = blockIdx.x*blockDim.x + threadIdx.x; i < n; i += gridDim.x*blockDim.x)
    p[i] = z;
}

// [B][C][H][W] fp32 -> [B][Hp][Wp][C] bf16 (channel-last), with spatial zero-pad
__global__ __launch_bounds__(256) void to_chlast(const float* __restrict__ src,
                                                 int sel, int Hp, int Wp, int pad) {
  unsigned short* dst = sel ? g_d2T : g_d1T;
  __shared__ unsigned short T[32*LDC];
  const int xt = blockIdx.x, y = blockIdx.y, b = blockIdx.z;
  const int x0 = xt*32;
  const int xg = threadIdx.x & 7, cq = threadIdx.x >> 3;   // cq in [0,32)
  #pragma unroll
  for (int it = 0; it < 3; ++it) {
    int c = it*32 + cq;
    const float4 v = *(const float4*)(src + (((b*C_ + c)*H_ + y)*W_ + x0 + xg*4));
    float vv[4] = {v.x, v.y, v.z, v.w};
    #pragma unroll
    for (int jj = 0; jj < 4; ++jj) {
      __hip_bfloat16 h = __float2bfloat16(vv[jj]);
      T[(xg*4 + jj)*LDC + c] = *(unsigned short*)&h;
    }
  }
  __syncthreads();
  for (int s = threadIdx.x; s < 32*12; s += 256) {
    int xi = s / 12, ch = s % 12;
    uint4 v = *(const uint4*)(&T[xi*LDC + ch*8]);
    *(uint4*)(dst + ((size_t)((b*Hp + pad + y)*Wp + pad + x0 + xi))*C_ + ch*8) = v;
  }
}

// One block per (b, y). 6 waves = (parity p, m-tile mt).
// Per parity p: A[u][c] = d1[b,c,y,2u+p] (48x96), B[w'][c] = d2[b,c,y+di,2w'+p-20].
// G = A·B^T band: out[b, i*21+j, y, 2u+p] = G[u, u+j], j in [0,21).
__global__ __launch_bounds__(384) void corr_main(const float* __restrict__ s1,
                                                 const float* __restrict__ s2,
                                                 const float* __restrict__ os,
                                                 float* __restrict__ out) {
  __shared__ unsigned short Alds[2*48*LDC];   // [p][u][c]
  __shared__ unsigned short Blds[2*80*LDC];   // [p][w'][c], w' < 80
  __shared__ float Dst[DD*LDST];              // [j][x] transpose-staging
  const int b = blockIdx.x & 7;               // b <-> XCD affinity (round-robin %8)
  const int y = blockIdx.x >> 3;

  // ---- stage A (once): d1T row -> [p][u][c] ----
  const unsigned short* d1row = g_d1T + (size_t)((b*H_ + y)*W_)*C_;
  for (int s = threadIdx.x; s < W_*12; s += 384) {
    int x = s / 12, ch = s % 12;
    uint4 v = *(const uint4*)(d1row + x*C_ + ch*8);
    *(uint4*)(&Alds[((x&1)*48 + (x>>1))*LDC + ch*8]) = v;
  }
  const int wave = threadIdx.x >> 6, lane = threadIdx.x & 63;
  const int p = wave & 1, m0 = (wave >> 1)*16;
  const int lr = lane & 15, lg = lane >> 4;
  const float scale = s1[0]*s2[0] / (96.0f * os[0]);
  __syncthreads();

  // A-fragments: constant across di -> load once.
  // A-frag layout: row m = lane&15, k = 8*(lane>>4)+i (8 contiguous c)
  sh8 aF[3];
  #pragma unroll
  for (int k = 0; k < 3; ++k)
    aF[k] = *(const sh8*)(&Alds[(p*48 + m0 + lr)*LDC + k*32 + lg*8]);

  for (int i = 0; i < DD; ++i) {
    // ---- stage B row for this di: yp = y + 2i (always in [0,104)) ----
    const unsigned short* d2row = g_d2T + (size_t)((b*D2T_H + (y + 2*i))*D2T_W)*C_;
    for (int s = threadIdx.x; s < D2T_W*12; s += 384) {
      int xp = s / 12, ch = s % 12;
      uint4 v = *(const uint4*)(d2row + xp*C_ + ch*8);
      *(uint4*)(&Blds[((xp&1)*80 + (xp>>1))*LDC + ch*8]) = v;
    }
    __syncthreads();

    // ---- 9 MFMA: 3 k-chunks x 3 n-tiles ----
    fx4 acc[3] = {fx4{0,0,0,0}, fx4{0,0,0,0}, fx4{0,0,0,0}};
    #pragma unroll
    for (int k = 0; k < 3; ++k) {
      #pragma unroll
      for (int n = 0; n < 3; ++n) {
        sh8 bF = *(const sh8*)(&Blds[(p*80 + m0 + n*16 + lr)*LDC + k*32 + lg*8]);
        acc[n] = __builtin_amdgcn_mfma_f32_16x16x32_bf16(aF[k], bF, acc[n], 0, 0, 0);
      }
    }

    // ---- band extract: D col = w' = m0+16n+lr, row = u = m0+4*lg+r ----
    #pragma unroll
    for (int n = 0; n < 3; ++n) {
      #pragma unroll
      for (int r = 0; r < 4; ++r) {
        int j = 16*n + lr - 4*lg - r;         // j = w' - u
        if (j >= 0 && j < DD)
          Dst[j*LDST + 2*(m0 + 4*lg + r) + p] = acc[n][r];
      }
    }
    __syncthreads();

    // ---- coalesced store: 21 planes x 96 x ----
    size_t obase = (size_t)((b*441 + i*21)*H_ + y)*W_;
    for (int s = threadIdx.x; s < DD*24; s += 384) {
      int j = s / 24, xg = s % 24;
      fx4 v = *(const fx4*)(&Dst[j*LDST + xg*4]);
      v = v * scale;
      *(fx4*)(out + obase + (size_t)j*H_*W_ + xg*4) = v;
    }
    __syncthreads();
  }
}

extern "C" void kernel_launch(void* const* d_in, const int* in_sizes, int n_in,
                              void* d_out, int out_size, void* d_ws, size_t ws_size,
                              hipStream_t stream) {
  const float* d1 = (const float*)d_in[0];
  const float* d2 = (const float*)d_in[1];
  const float* s1 = (const float*)d_in[2];
  const float* s2 = (const float*)d_in[3];
  const float* os = (const float*)d_in[5];   // inter_scale (d_in[4]) unused by reference

  zfill_d2T<<<1664, 256, 0, stream>>>();
  to_chlast<<<dim3(3, H_, B_), 256, 0, stream>>>(d1, 0, H_, W_, 0);
  to_chlast<<<dim3(3, H_, B_), 256, 0, stream>>>(d2, 1, D2T_H, D2T_W, 20);
  corr_main<<<B_*H_, 384, 0, stream>>>(s1, s2, os, (float*)d_out);
}

// Round 2
// 106.981 us; speedup vs baseline: 1.1247x; 1.1247x over previous
//
#include <hip/hip_runtime.h>
#include <hip/hip_bf16.h>

#define B_ 8
#define C_ 96
#define H_ 64
#define W_ 96
#define DD 21            // displacements per axis
#define D2T_H 104        // 64 + 2*20
#define D2T_W 160        // 96 + 2*20 + 24 extra zero cols for n-tile overreach
#define LDST 100         // Dst row stride in floats (16B aligned)
#define ISPLIT 3
#define NI 7             // DD / ISPLIT

typedef __attribute__((ext_vector_type(8))) short sh8;
typedef __attribute__((ext_vector_type(4))) float fx4;

__device__ __attribute__((aligned(16))) unsigned short g_d1T[B_*H_*W_*C_];
__device__ __attribute__((aligned(16))) unsigned short g_d2T[(size_t)B_*D2T_H*D2T_W*C_];

// Zero only the border of g_d2T (interior is fully overwritten by to_chlast).
__global__ __launch_bounds__(256) void zfill_border() {
  // region0: rows [0,20) u [84,104), all 160 cols -> 40*160 cells
  // region1: rows [20,84), cols [0,20) u [116,160) -> 64*64 cells
  const int per_b = 40*160 + 64*64;          // 10496 cells
  const int total = B_ * per_b * 12;         // 12 uint4 per cell (96 ch * 2B)
  uint4 z; z.x = z.y = z.z = z.w = 0u;
  for (int idx = blockIdx.x*256 + threadIdx.x; idx < total; idx += gridDim.x*256) {
    int ch = idx % 12, cell = idx / 12;
    int b = cell / per_b, s = cell % per_b;
    int r, c;
    if (s < 40*160) { int r0 = s / 160; c = s % 160; r = (r0 < 20) ? r0 : r0 + 64; }
    else { int t = s - 40*160; r = 20 + t / 64; int c1 = t % 64; c = (c1 < 20) ? c1 : c1 + 96; }
    *(uint4*)(g_d2T + ((size_t)((b*D2T_H + r)*D2T_W + c))*C_ + ch*8) = z;
  }
}

// [B][C][H][W] fp32 -> [B][Hp][Wp][C] bf16 (channel-last), with spatial zero-pad
#define LDC 104
__global__ __launch_bounds__(256) void to_chlast(const float* __restrict__ src,
                                                 int sel, int Hp, int Wp, int pad) {
  unsigned short* dst = sel ? g_d2T : g_d1T;
  __shared__ unsigned short T[32*LDC];
  const int xt = blockIdx.x, y = blockIdx.y, b = blockIdx.z;
  const int x0 = xt*32;
  const int xg = threadIdx.x & 7, cq = threadIdx.x >> 3;   // cq in [0,32)
  #pragma unroll
  for (int it = 0; it < 3; ++it) {
    int c = it*32 + cq;
    const float4 v = *(const float4*)(src + (((b*C_ + c)*H_ + y)*W_ + x0 + xg*4));
    float vv[4] = {v.x, v.y, v.z, v.w};
    #pragma unroll
    for (int jj = 0; jj < 4; ++jj) {
      __hip_bfloat16 h = __float2bfloat16(vv[jj]);
      T[(xg*4 + jj)*LDC + c] = *(unsigned short*)&h;
    }
  }
  __syncthreads();
  for (int s = threadIdx.x; s < 32*12; s += 256) {
    int xi = s / 12, ch = s % 12;
    uint4 v = *(const uint4*)(&T[xi*LDC + ch*8]);
    *(uint4*)(dst + ((size_t)((b*Hp + pad + y)*Wp + pad + x0 + xi))*C_ + ch*8) = v;
  }
}

// One block per (b, y, i-segment). 6 waves = (parity p, m-tile).
// Per parity p: A[u][c] = d1[b,c,y,2u+p] (48x96), B[w'][c] = d2pad[b,c,y+2i,2w'+p].
// G = A·B^T band: out[b, i*21+j, y, 2u+p] = G[u, u+j], j in [0,21).
// No LDS staging of A/B: fragments come straight from global (per-XCD L2-resident).
__global__ __launch_bounds__(384) void corr_main(const float* __restrict__ s1,
                                                 const float* __restrict__ s2,
                                                 const float* __restrict__ os,
                                                 float* __restrict__ out) {
  __shared__ float Dst[2][DD*LDST];
  const int gid = blockIdx.x;
  const int b = gid & 7;                     // b <-> XCD affinity
  const int y = (gid >> 3) & 63;
  const int i0 = (gid >> 9) * NI;
  const int wave = threadIdx.x >> 6, lane = threadIdx.x & 63;
  const int p = wave & 1, m0 = (wave >> 1) << 4;
  const int lr = lane & 15, lg = lane >> 4;
  const float scale = s1[0]*s2[0] / (96.0f * os[0]);

  // A fragments (constant across i): row u = m0+lr  ->  x = 2u+p
  const unsigned short* d1row = g_d1T + (size_t)((b*H_ + y)*W_)*C_;
  const int xa = 2*(m0 + lr) + p;
  sh8 aF[3];
  #pragma unroll
  for (int k = 0; k < 3; ++k)
    aF[k] = *(const sh8*)(d1row + xa*C_ + k*32 + lg*8);

  const unsigned short* d2base = g_d2T + (size_t)(b*D2T_H)*D2T_W*C_;
  const int xb = 2*(m0 + lr) + p;            // col for n-tile 0; +32 per n

  sh8 bFa[9], bFb[9];
  auto loadB = [&](sh8* bf, int i) {
    const unsigned short* row = d2base + (size_t)(y + 2*i)*D2T_W*C_;
    #pragma unroll
    for (int k = 0; k < 3; ++k)
      #pragma unroll
      for (int n = 0; n < 3; ++n)
        bf[k*3+n] = *(const sh8*)(row + (xb + 32*n)*C_ + k*32 + lg*8);
  };

  auto step = [&](const sh8* bf, int i, int buf) {
    fx4 acc[3] = {fx4{0,0,0,0}, fx4{0,0,0,0}, fx4{0,0,0,0}};
    #pragma unroll
    for (int k = 0; k < 3; ++k)
      #pragma unroll
      for (int n = 0; n < 3; ++n)
        acc[n] = __builtin_amdgcn_mfma_f32_16x16x32_bf16(aF[k], bf[k*3+n], acc[n], 0, 0, 0);

    // band extract: D col = w' = m0+16n+lr, row = u = m0+4lg+r ; j = w'-u
    #pragma unroll
    for (int n = 0; n < 3; ++n)
      #pragma unroll
      for (int r = 0; r < 4; ++r) {
        int j = 16*n + lr - 4*lg - r;
        if (j >= 0 && j < DD) {
          int x = 2*(m0 + 4*lg + r) + p;
          Dst[buf][j*LDST + (x ^ ((j & 7) << 2))] = acc[n][r];
        }
      }
    __syncthreads();

    // coalesced store: 21 planes x 96 x (reads undo the XOR swizzle, fx4-aligned)
    size_t obase = (size_t)((b*441 + i*DD)*H_ + y)*W_;
    for (int s = threadIdx.x; s < DD*24; s += 384) {
      int j = s / 24, xg = s % 24;
      fx4 v = *(const fx4*)(&Dst[buf][j*LDST + ((xg*4) ^ ((j & 7) << 2))]);
      v = v * scale;
      *(fx4*)(out + obase + (size_t)j*H_*W_ + xg*4) = v;
    }
    // no trailing barrier: next step writes the OTHER buffer; the following
    // barrier (inside next step) orders its readers. Ping-pong is race-free
    // with one __syncthreads per iteration.
  };

  loadB(bFa, i0);
  #pragma unroll
  for (int t = 0; t < NI; t += 2) {
    if (t + 1 < NI) loadB(bFb, i0 + t + 1);
    step(bFa, i0 + t, 0);
    if (t + 1 < NI) {
      if (t + 2 < NI) loadB(bFa, i0 + t + 2);
      step(bFb, i0 + t + 1, 1);
    }
  }
}

extern "C" void kernel_launch(void* const* d_in, const int* in_sizes, int n_in,
                              void* d_out, int out_size, void* d_ws, size_t ws_size,
                              hipStream_t stream) {
  const float* d1 = (const float*)d_in[0];
  const float* d2 = (const float*)d_in[1];
  const float* s1 = (const float*)d_in[2];
  const float* s2 = (const float*)d_in[3];
  const float* os = (const float*)d_in[5];   // inter_scale (d_in[4]) unused by reference

  zfill_border<<<2048, 256, 0, stream>>>();
  to_chlast<<<dim3(3, H_, B_), 256, 0, stream>>>(d1, 0, H_, W_, 0);
  to_chlast<<<dim3(3, H_, B_), 256, 0, stream>>>(d2, 1, D2T_H, D2T_W, 20);
  corr_main<<<B_*H_*ISPLIT, 384, 0, stream>>>(s1, s2, os, (float*)d_out);
}

// Round 3
// 59.015 us; speedup vs baseline: 2.0388x; 1.8128x over previous
//
#include <hip/hip_runtime.h>
#include <hip/hip_bf16.h>

#define B_ 8
#define C_ 96
#define H_ 64
#define W_ 96
#define DD 21
#define NI 3
#define ISPLIT 7
#define LDSTm 37           // Dst row stride (floats): 5 mod 32 -> conflict-free scatter

typedef __attribute__((ext_vector_type(8))) short sh8;
typedef __attribute__((ext_vector_type(4))) float fx4;

// Fragment-major bf16 tensors: innermost [lane(64)][e(8)] = 1KB per k-block,
// so a wave's MFMA operand load is base + lane*16B (fully coalesced).
// d1F: [b][y][p][ut(3)][k(3)][lane][8]
// d2F: [b][yp(104)][p][wt(5)][k(3)][lane][8]   (yp/x padded, borders zero)
__device__ __attribute__((aligned(16))) unsigned short g_d1F[B_*H_*2*3*3*512];
__device__ __attribute__((aligned(16))) unsigned short g_d2F[(size_t)B_*104*2*5*3*512];

// Zero the 40 border rows (yp<20, yp>=84) of d2F.
__global__ __launch_bounds__(256) void zfill_rows() {
  const int per_row = 2*5*3*512/8;          // 1920 uint4 per (b,yp)
  const int total = B_*40*per_row;
  uint4 z; z.x = z.y = z.z = z.w = 0u;
  for (int idx = blockIdx.x*256 + threadIdx.x; idx < total; idx += gridDim.x*256) {
    int s = idx % per_row, rr = idx / per_row;
    int b = rr / 40, r0 = rr % 40;
    int yp = (r0 < 20) ? r0 : r0 + 64;
    *((uint4*)(g_d2F + (size_t)(b*104 + yp)*(2*5*3*512)) + s) = z;
  }
}

// [B][C][H][W] fp32 -> fragment-major bf16. One block per (b,y).
__global__ __launch_bounds__(256) void prep_d1(const float* __restrict__ src) {
  __shared__ unsigned int raw[C_*48];       // [c][w] packed (p0 | p1<<16)
  const int y = blockIdx.x, b = blockIdx.y;
  for (int idx = threadIdx.x; idx < C_*48; idx += 256) {
    int c = idx / 48, w = idx % 48;
    const float2 v = *(const float2*)(src + (((b*C_ + c)*H_ + y)*W_ + 2*w));
    __hip_bfloat16 h0 = __float2bfloat16(v.x), h1 = __float2bfloat16(v.y);
    raw[idx] = (unsigned)*(unsigned short*)&h0 | ((unsigned)*(unsigned short*)&h1 << 16);
  }
  __syncthreads();
  unsigned short* ob = g_d1F + (size_t)(b*H_ + y)*(2*9*512);
  for (int s = threadIdx.x; s < 2*9*64; s += 256) {
    int lane = s & 63, q = s >> 6;
    int kk = q % 3, ut = (q/3) % 3, p = q / 9;
    int w = ut*16 + (lane & 15);
    int cb = kk*32 + (lane >> 4)*8;
    unsigned short tmp[8];
    #pragma unroll
    for (int e = 0; e < 8; ++e) {
      unsigned pk = raw[(cb + e)*48 + w];
      tmp[e] = (unsigned short)(p ? (pk >> 16) : pk);
    }
    *(uint4*)(ob + (size_t)s*8) = *(const uint4*)tmp;
  }
}

__global__ __launch_bounds__(256) void prep_d2(const float* __restrict__ src) {
  __shared__ unsigned int raw[C_*48];
  const int y = blockIdx.x, b = blockIdx.y;
  for (int idx = threadIdx.x; idx < C_*48; idx += 256) {
    int c = idx / 48, w = idx % 48;
    const float2 v = *(const float2*)(src + (((b*C_ + c)*H_ + y)*W_ + 2*w));
    __hip_bfloat16 h0 = __float2bfloat16(v.x), h1 = __float2bfloat16(v.y);
    raw[idx] = (unsigned)*(unsigned short*)&h0 | ((unsigned)*(unsigned short*)&h1 << 16);
  }
  __syncthreads();
  unsigned short* ob = g_d2F + (size_t)(b*104 + y + 20)*(2*15*512);
  for (int s = threadIdx.x; s < 2*15*64; s += 256) {
    int lane = s & 63, q = s >> 6;
    int kk = q % 3, wt = (q/3) % 5, p = q / 15;
    int w = wt*16 + (lane & 15) - 10;      // x-pad: w'_global = w + 10
    int cb = kk*32 + (lane >> 4)*8;
    uint4 o; o.x = o.y = o.z = o.w = 0u;
    if (w >= 0 && w < 48) {
      unsigned short tmp[8];
      #pragma unroll
      for (int e = 0; e < 8; ++e) {
        unsigned pk = raw[(cb + e)*48 + w];
        tmp[e] = (unsigned short)(p ? (pk >> 16) : pk);
      }
      o = *(const uint4*)tmp;
    }
    *(uint4*)(ob + (size_t)s*8) = o;
  }
}

// One block per (b, m-tile, y, i-segment): 128 threads = 2 waves (p=0,1).
// Wave (p): A[u][c]=d1[b,c,y,2u+p], u in [m0,m0+16); B[w'][c]=d2pad[...,2w'+p].
// G=A·B^T band: out[b, i*21+j, y, 2u+p] = G[u, u+j].
__global__ __launch_bounds__(128, 4) void corr_main(const float* __restrict__ s1,
                                                    const float* __restrict__ s2,
                                                    const float* __restrict__ os,
                                                    float* __restrict__ out) {
  __shared__ float Dst[2][DD*LDSTm];
  const int gid = blockIdx.x;
  const int b = gid & 7;                   // XCD affinity
  int t = gid >> 3;
  const int m0 = (t % 3) << 4; t /= 3;
  const int y = t & 63;
  const int i0 = (t >> 6) * NI;
  const int p = threadIdx.x >> 6;
  const int lane = threadIdx.x & 63;
  const int lr = lane & 15, lg = lane >> 4;
  const float scale = s1[0]*s2[0] / (96.0f * os[0]);

  const unsigned short* aB =
      g_d1F + (size_t)((b*H_ + y)*2 + p)*(9*512) + (size_t)(m0 >> 4)*3*512 + lane*8;
  sh8 aF[3];
  #pragma unroll
  for (int k = 0; k < 3; ++k)
    aF[k] = *(const sh8*)(aB + k*512);

  sh8 bFa[9], bFb[9];
  auto loadB = [&](sh8* bf, int i) {
    const unsigned short* rb =
        g_d2F + (size_t)(((b*104 + y + 2*i)*2 + p)*5 + (m0 >> 4))*(3*512) + lane*8;
    #pragma unroll
    for (int n = 0; n < 3; ++n)
      #pragma unroll
      for (int k = 0; k < 3; ++k)
        bf[k*3+n] = *(const sh8*)(rb + (n*3 + k)*512);
  };

  auto step = [&](const sh8* bf, int i, int buf) {
    fx4 acc[3] = {fx4{0,0,0,0}, fx4{0,0,0,0}, fx4{0,0,0,0}};
    #pragma unroll
    for (int k = 0; k < 3; ++k)
      #pragma unroll
      for (int n = 0; n < 3; ++n)
        acc[n] = __builtin_amdgcn_mfma_f32_16x16x32_bf16(aF[k], bf[k*3+n], acc[n], 0, 0, 0);
    // band extract: col w' = m0+16n+lr, row u = m0+4lg+r ; j = w'-u, xl = x-2m0
    #pragma unroll
    for (int n = 0; n < 3; ++n)
      #pragma unroll
      for (int r = 0; r < 4; ++r) {
        int j = 16*n + lr - 4*lg - r;
        if (j >= 0 && j < DD)
          Dst[buf][j*LDSTm + 2*(4*lg + r) + p] = acc[n][r];
      }
    __syncthreads();
    // store this block's 21 x 32 sub-plane (contiguous 128B rows)
    size_t obase = (size_t)((b*441 + i*DD)*H_ + y)*W_ + 2*m0;
    for (int s = threadIdx.x; s < DD*32; s += 128) {
      int j = s >> 5, xl = s & 31;
      out[obase + (size_t)j*(H_*W_) + xl] = Dst[buf][j*LDSTm + xl] * scale;
    }
    // no trailing barrier: ping-pong buffers + next step's barrier order reuse
  };

  loadB(bFa, i0);
  loadB(bFb, i0 + 1);
  step(bFa, i0, 0);
  loadB(bFa, i0 + 2);
  step(bFb, i0 + 1, 1);
  step(bFa, i0 + 2, 0);
}

extern "C" void kernel_launch(void* const* d_in, const int* in_sizes, int n_in,
                              void* d_out, int out_size, void* d_ws, size_t ws_size,
                              hipStream_t stream) {
  const float* d1 = (const float*)d_in[0];
  const float* d2 = (const float*)d_in[1];
  const float* s1 = (const float*)d_in[2];
  const float* s2 = (const float*)d_in[3];
  const float* os = (const float*)d_in[5];   // inter_scale (d_in[4]) unused

  zfill_rows<<<2048, 256, 0, stream>>>();
  prep_d1<<<dim3(H_, B_), 256, 0, stream>>>(d1);
  prep_d2<<<dim3(H_, B_), 256, 0, stream>>>(d2);
  corr_main<<<B_*3*H_*ISPLIT, 128, 0, stream>>>(s1, s2, os, (float*)d_out);
}

// Round 4
// 51.439 us; speedup vs baseline: 2.3391x; 1.1473x over previous
//
#include <hip/hip_runtime.h>
#include <hip/hip_bf16.h>

#define B_ 8
#define C_ 96
#define H_ 64
#define W_ 96
#define DD 21
#define NI 3
#define ISPLIT 7
#define LDSTm 37           // Dst row stride (floats): 5 mod 32 -> conflict-light scatter
#define RAWS 49            // prep LDS row stride (uints): lg-jump 392 % 32 = 8 -> conflict-free

typedef __attribute__((ext_vector_type(8))) short sh8;
typedef __attribute__((ext_vector_type(4))) float fx4;

// Fragment-major bf16 tensors: innermost [lane(64)][e(8)] = 1KB per k-block,
// so a wave's MFMA operand load is base + lane*16B (fully coalesced).
// d1F: [b][y][p][ut(3)][k(3)][lane][8]
// d2F: [b][yp(104)][p][wt(5)][k(3)][lane][8]   (yp/x padded, borders zero)
__device__ __attribute__((aligned(16))) unsigned short g_d1F[B_*H_*2*3*3*512];
__device__ __attribute__((aligned(16))) unsigned short g_d2F[(size_t)B_*104*2*5*3*512];

// One fused prep kernel: grid (168, B).
//  t in [0,64):    d1 row y=t          -> g_d1F
//  t in [64,168):  d2 padded row yp=t-64 (zero-fill if border) -> g_d2F
__global__ __launch_bounds__(256) void prep_all(const float* __restrict__ d1,
                                                const float* __restrict__ d2) {
  __shared__ unsigned int raw[C_*RAWS];    // [c][w] packed (p0 | p1<<16)
  const int b = blockIdx.y;
  const int t = blockIdx.x;

  if (t >= 64) {
    const int yp = t - 64;
    unsigned short* ob = g_d2F + (size_t)(b*104 + yp)*(2*15*512);
    if (yp < 20 || yp >= 84) {             // border row: pure zero-fill
      uint4 z; z.x = z.y = z.z = z.w = 0u;
      for (int s = threadIdx.x; s < 1920; s += 256)
        *((uint4*)ob + s) = z;
      return;
    }
    const int y = yp - 20;
    for (int idx = threadIdx.x; idx < C_*48; idx += 256) {
      int c = idx / 48, w = idx % 48;
      const float2 v = *(const float2*)(d2 + (((b*C_ + c)*H_ + y)*W_ + 2*w));
      __hip_bfloat16 h0 = __float2bfloat16(v.x), h1 = __float2bfloat16(v.y);
      raw[c*RAWS + w] = (unsigned)*(unsigned short*)&h0 |
                        ((unsigned)*(unsigned short*)&h1 << 16);
    }
    __syncthreads();
    for (int s = threadIdx.x; s < 2*15*64; s += 256) {
      int lane = s & 63, q = s >> 6;
      int kk = q % 3, wt = (q/3) % 5, p = q / 15;
      int w = wt*16 + (lane & 15) - 10;    // x-pad: stored col = w' - 10
      int cb = kk*32 + (lane >> 4)*8;
      uint4 o; o.x = o.y = o.z = o.w = 0u;
      if (w >= 0 && w < 48) {
        unsigned short tmp[8];
        #pragma unroll
        for (int e = 0; e < 8; ++e) {
          unsigned pk = raw[(cb + e)*RAWS + w];
          tmp[e] = (unsigned short)(p ? (pk >> 16) : pk);
        }
        o = *(const uint4*)tmp;
      }
      *(uint4*)(ob + (size_t)s*8) = o;
    }
  } else {
    const int y = t;
    for (int idx = threadIdx.x; idx < C_*48; idx += 256) {
      int c = idx / 48, w = idx % 48;
      const float2 v = *(const float2*)(d1 + (((b*C_ + c)*H_ + y)*W_ + 2*w));
      __hip_bfloat16 h0 = __float2bfloat16(v.x), h1 = __float2bfloat16(v.y);
      raw[c*RAWS + w] = (unsigned)*(unsigned short*)&h0 |
                        ((unsigned)*(unsigned short*)&h1 << 16);
    }
    __syncthreads();
    unsigned short* ob = g_d1F + (size_t)(b*H_ + y)*(2*9*512);
    for (int s = threadIdx.x; s < 2*9*64; s += 256) {
      int lane = s & 63, q = s >> 6;
      int kk = q % 3, ut = (q/3) % 3, p = q / 9;
      int w = ut*16 + (lane & 15);
      int cb = kk*32 + (lane >> 4)*8;
      unsigned short tmp[8];
      #pragma unroll
      for (int e = 0; e < 8; ++e) {
        unsigned pk = raw[(cb + e)*RAWS + w];
        tmp[e] = (unsigned short)(p ? (pk >> 16) : pk);
      }
      *(uint4*)(ob + (size_t)s*8) = *(const uint4*)tmp;
    }
  }
}

// One block per (b, m-tile, y, i-segment): 128 threads = 2 waves (p=0,1).
// Wave (p): A[u][c]=d1[b,c,y,2u+p], u in [m0,m0+16); B[w'][c]=d2pad[...,2w'+p].
// G=A·B^T band: out[b, i*21+j, y, 2u+p] = G[u, u+j], j in [0,21).
// Single-buffered B loads; latency hidden by TLP (~24 waves/CU).
__global__ __launch_bounds__(128, 6) void corr_main(const float* __restrict__ s1,
                                                    const float* __restrict__ s2,
                                                    const float* __restrict__ os,
                                                    float* __restrict__ out) {
  __shared__ float Dst[2][DD*LDSTm];
  const int gid = blockIdx.x;
  const int b = gid & 7;                   // XCD affinity
  int t = gid >> 3;
  const int m0 = (t % 3) << 4; t /= 3;
  const int y = t & 63;
  const int i0 = (t >> 6) * NI;
  const int p = threadIdx.x >> 6;
  const int lane = threadIdx.x & 63;
  const int lr = lane & 15, lg = lane >> 4;
  const float scale = s1[0]*s2[0] / (96.0f * os[0]);

  const unsigned short* aB =
      g_d1F + (size_t)((b*H_ + y)*2 + p)*(9*512) + (size_t)(m0 >> 4)*3*512 + lane*8;
  sh8 aF[3];
  #pragma unroll
  for (int k = 0; k < 3; ++k)
    aF[k] = *(const sh8*)(aB + k*512);

  for (int it = 0; it < NI; ++it) {
    const int i = i0 + it;
    const unsigned short* rb =
        g_d2F + (size_t)(((b*104 + y + 2*i)*2 + p)*5 + (m0 >> 4))*(3*512) + lane*8;
    sh8 bF[9];
    #pragma unroll
    for (int n = 0; n < 3; ++n)
      #pragma unroll
      for (int k = 0; k < 3; ++k)
        bF[k*3+n] = *(const sh8*)(rb + (n*3 + k)*512);

    fx4 acc[3] = {fx4{0,0,0,0}, fx4{0,0,0,0}, fx4{0,0,0,0}};
    #pragma unroll
    for (int k = 0; k < 3; ++k)
      #pragma unroll
      for (int n = 0; n < 3; ++n)
        acc[n] = __builtin_amdgcn_mfma_f32_16x16x32_bf16(aF[k], bF[k*3+n], acc[n], 0, 0, 0);

    // band extract: col w' = m0+16n+lr, row u = m0+4lg+r ; j = w'-u, x = 2u+p
    const int buf = it & 1;
    #pragma unroll
    for (int n = 0; n < 3; ++n)
      #pragma unroll
      for (int r = 0; r < 4; ++r) {
        int j = 16*n + lr - 4*lg - r;
        if (j >= 0 && j < DD)
          Dst[buf][j*LDSTm + 2*(4*lg + r) + p] = acc[n][r];
      }
    __syncthreads();

    // store this block's 21 x 32 sub-plane (contiguous 128B rows)
    size_t obase = (size_t)((b*441 + i*DD)*H_ + y)*W_ + 2*m0;
    for (int s = threadIdx.x; s < DD*32; s += 128) {
      int j = s >> 5, xl = s & 31;
      out[obase + (size_t)j*(H_*W_) + xl] = Dst[buf][j*LDSTm + xl] * scale;
    }
    // no trailing barrier: ping-pong buffers + next iteration's barrier
    // (after its extract) orders buffer reuse. Race-free with 1 barrier/iter.
  }
}

extern "C" void kernel_launch(void* const* d_in, const int* in_sizes, int n_in,
                              void* d_out, int out_size, void* d_ws, size_t ws_size,
                              hipStream_t stream) {
  const float* d1 = (const float*)d_in[0];
  const float* d2 = (const float*)d_in[1];
  const float* s1 = (const float*)d_in[2];
  const float* s2 = (const float*)d_in[3];
  const float* os = (const float*)d_in[5];   // inter_scale (d_in[4]) unused

  prep_all<<<dim3(168, B_), 256, 0, stream>>>(d1, d2);
  corr_main<<<B_*3*H_*ISPLIT, 128, 0, stream>>>(s1, s2, os, (float*)d_out);
}